// Round 2
// baseline (20994.998 us; speedup 1.0000x reference)
//
#include <hip/hip_runtime.h>
#include <cstdint>
#include <cstddef>

typedef float f32x4 __attribute__((ext_vector_type(4)));
typedef __bf16 bf16x8 __attribute__((ext_vector_type(8)));

#define T_STEPS 256
#define HD      1024
#define DHK     2048

__device__ __forceinline__ unsigned short f2bf(float f) {
  union { float f; unsigned u; } v; v.f = f;
  unsigned r = v.u + 0x7fffu + ((v.u >> 16) & 1u);  // RNE, inputs finite
  return (unsigned short)(r >> 16);
}

__device__ __forceinline__ float fast_sigmoid(float x) {
  return 1.0f / (1.0f + __expf(-x));
}
__device__ __forceinline__ float fast_tanh(float x) {
  float e = __expf(2.0f * x);
  return (e - 1.0f) / (e + 1.0f);
}

__device__ __forceinline__ f32x4 mfma16(bf16x8 a, bf16x8 b, f32x4 c) {
  return __builtin_amdgcn_mfma_f32_16x16x32_bf16(a, b, c, 0, 0, 0);
}

// Producer: all data stores drained (caller did __syncthreads), flush L2,
// then L2-bypassing flag store so remote XCD pollers see it.
__device__ __forceinline__ void release_flag(int* f, int v) {
  __builtin_amdgcn_fence(__ATOMIC_RELEASE, "agent");   // waitcnt + buffer_wbl2
  __hip_atomic_store(f, v, __ATOMIC_RELAXED, __HIP_MEMORY_SCOPE_AGENT);
}
// Consumer poll: relaxed agent loads bypass the (non-coherent) local L2.
__device__ __forceinline__ void wait_ge(const int* f, int v) {
  while (__hip_atomic_load(f, __ATOMIC_RELAXED, __HIP_MEMORY_SCOPE_AGENT) < v)
    __builtin_amdgcn_s_sleep(2);
}

// ---- persistent kernel: all 256 timesteps, 256 blocks (1/CU), 4 waves -----
// Per phase: 64x16 output tile per block, waves K-split, LDS reduce.
//   A: G[gate*64+b][h]   = act(comb @ W[n0..n0+16]^T + bias)   K=2048
//   B: G2[gate*64+b][h]  = tanh(G @ qcw0[n0..]^T + qcb0)       K=1024
//   C: rows (gate,16-batch) -> f/i/g/o in one thread -> cell update, K=1024
__global__ __launch_bounds__(256, 1) void qlstm_persist(
    const unsigned short* __restrict__ Xbf,
    const unsigned short* __restrict__ Wbf,      // [4096][2048]
    const unsigned short* __restrict__ qcw,      // [2][1024][1024]
    const float* __restrict__ bias_cat,          // [4096]
    const float* __restrict__ qcb,               // [2][1024]
    unsigned short* __restrict__ Gbf,            // [256][1024]
    unsigned short* __restrict__ G2bf,           // [256][1024]
    unsigned short* __restrict__ hbf,            // [64][1024]
    float* __restrict__ c_state,                 // [64][1024]
    float* __restrict__ out,
    int* __restrict__ aA, int* __restrict__ aB, int* __restrict__ aC) {
  const int nb = blockIdx.x, tid = threadIdx.x;
  const int wv = tid >> 6, lane = tid & 63;
  const int l15 = lane & 15, l16 = lane >> 4;
  const int q = nb >> 6;            // A: gate | B: row-gate | C: batch-tile
  const int n0 = (nb & 63) * 16;    // col offset within 1024
  const int kb = wv * 256;          // wave K-slice base

  __shared__ __align__(16) float red[4][16][68];  // [wave][col][row(padded)]

  // ---- weight/bias preload into registers (held across all 256 steps) ----
  bf16x8 wA[16], wB[8], wC[8];
  {
    const unsigned short* wrow = Wbf + (size_t)(nb * 16 + l15) * DHK;
#pragma unroll
    for (int s = 0; s < 8; ++s)
      wA[s] = *(const bf16x8*)&wrow[kb + s * 32 + l16 * 8];
#pragma unroll
    for (int s = 0; s < 8; ++s)
      wA[8 + s] = *(const bf16x8*)&wrow[1024 + kb + s * 32 + l16 * 8];
    const unsigned short* qrow0 = qcw + (size_t)(n0 + l15) * HD;
    const unsigned short* qrow1 = qrow0 + (size_t)HD * HD;
#pragma unroll
    for (int s = 0; s < 8; ++s) {
      wB[s] = *(const bf16x8*)&qrow0[kb + s * 32 + l16 * 8];
      wC[s] = *(const bf16x8*)&qrow1[kb + s * 32 + l16 * 8];
    }
  }
  const f32x4 biasA = *(const f32x4*)&bias_cat[nb * 16 + (tid & 3) * 4];
  const f32x4 biasB = *(const f32x4*)&qcb[n0 + (tid & 3) * 4];
  const float biasC = qcb[HD + n0 + (tid & 15)];

  const int erow = tid >> 2, ecb = (tid & 3) * 4;  // A/B epilogue coords
  const int bl = tid >> 4, cc = tid & 15;          // C epilogue coords

  for (int t = 0; t < T_STEPS; ++t) {
    // ================= phase A: gates =================
    {
      f32x4 acc[4] = {};
      // x-half first: independent of the recurrence -> overlaps handoff wait
      const unsigned short* xb = Xbf + (size_t)t * (64 * HD);
#pragma unroll
      for (int s = 0; s < 8; ++s) {
        const int k = kb + s * 32 + l16 * 8;
#pragma unroll
        for (int mt = 0; mt < 4; ++mt) {
          bf16x8 a = *(const bf16x8*)&xb[(size_t)(mt * 16 + l15) * HD + k];
          acc[mt] = mfma16(a, wA[s], acc[mt]);
        }
      }
      wait_ge(&aC[tid], t);                       // h(t-1) ready (all C blocks)
      __syncthreads();
      __builtin_amdgcn_fence(__ATOMIC_ACQUIRE, "agent");
#pragma unroll
      for (int s = 0; s < 8; ++s) {
        const int k = kb + s * 32 + l16 * 8;
#pragma unroll
        for (int mt = 0; mt < 4; ++mt) {
          bf16x8 a = *(const bf16x8*)&hbf[(size_t)(mt * 16 + l15) * HD + k];
          acc[mt] = mfma16(a, wA[8 + s], acc[mt]);
        }
      }
      __syncthreads();
#pragma unroll
      for (int mt = 0; mt < 4; ++mt)
        *(f32x4*)&red[wv][l15][mt * 16 + l16 * 4] = acc[mt];
      __syncthreads();
      ushort4 pk;
#pragma unroll
      for (int i = 0; i < 4; ++i) {
        float v = red[0][ecb + i][erow] + red[1][ecb + i][erow] +
                  red[2][ecb + i][erow] + red[3][ecb + i][erow] + biasA[i];
        v = (q == 2) ? fast_tanh(v) : fast_sigmoid(v);
        ((unsigned short*)&pk)[i] = f2bf(v);
      }
      *(ushort4*)&Gbf[(size_t)(q * 64 + erow) * HD + n0 + ecb] = pk;
      __syncthreads();
      if (tid == 0) release_flag(&aA[nb], t + 1);
    }
    // ================= phase B: qc depth 0 =================
    {
      if (tid < 64) wait_ge(&aA[q * 64 + tid], t + 1);  // only our gate's rows
      __syncthreads();
      __builtin_amdgcn_fence(__ATOMIC_ACQUIRE, "agent");
      f32x4 acc[4] = {};
      const unsigned short* gb = Gbf + (size_t)(q * 64) * HD;
#pragma unroll
      for (int s = 0; s < 8; ++s) {
        const int k = kb + s * 32 + l16 * 8;
#pragma unroll
        for (int mt = 0; mt < 4; ++mt) {
          bf16x8 a = *(const bf16x8*)&gb[(size_t)(mt * 16 + l15) * HD + k];
          acc[mt] = mfma16(a, wB[s], acc[mt]);
        }
      }
      __syncthreads();
#pragma unroll
      for (int mt = 0; mt < 4; ++mt)
        *(f32x4*)&red[wv][l15][mt * 16 + l16 * 4] = acc[mt];
      __syncthreads();
      ushort4 pk;
#pragma unroll
      for (int i = 0; i < 4; ++i) {
        float v = red[0][ecb + i][erow] + red[1][ecb + i][erow] +
                  red[2][ecb + i][erow] + red[3][ecb + i][erow] + biasB[i];
        ((unsigned short*)&pk)[i] = f2bf(fast_tanh(v));
      }
      *(ushort4*)&G2bf[(size_t)(q * 64 + erow) * HD + n0 + ecb] = pk;
      __syncthreads();
      if (tid == 0) release_flag(&aB[nb], t + 1);
    }
    // ================= phase C: qc depth 1 + cell update =================
    {
      wait_ge(&aB[tid], t + 1);                   // needs all of G2's K
      __syncthreads();
      __builtin_amdgcn_fence(__ATOMIC_ACQUIRE, "agent");
      f32x4 acc[4] = {};
#pragma unroll
      for (int s = 0; s < 8; ++s) {
        const int k = kb + s * 32 + l16 * 8;
#pragma unroll
        for (int mt = 0; mt < 4; ++mt) {  // mt = gate; rows = batch q*16+l15
          bf16x8 a =
              *(const bf16x8*)&G2bf[(size_t)(mt * 64 + q * 16 + l15) * HD + k];
          acc[mt] = mfma16(a, wC[s], acc[mt]);
        }
      }
      __syncthreads();
#pragma unroll
      for (int mt = 0; mt < 4; ++mt)
        *(f32x4*)&red[wv][l15][mt * 16 + l16 * 4] = acc[mt];
      __syncthreads();
      float gv[4];
#pragma unroll
      for (int g = 0; g < 4; ++g) {
        float v = red[0][cc][g * 16 + bl] + red[1][cc][g * 16 + bl] +
                  red[2][cc][g * 16 + bl] + red[3][cc][g * 16 + bl] + biasC;
        gv[g] = fast_tanh(v);
      }
      const int ci = (q * 16 + bl) * HD + n0 + cc;
      const float c_new = gv[0] * c_state[ci] + gv[1] * gv[2];
      const float h_new = gv[3] * fast_tanh(c_new);
      c_state[ci] = c_new;
      out[(size_t)t * (64 * HD) + ci] = h_new;
      hbf[ci] = f2bf(h_new);
      if (t == T_STEPS - 1) {
        out[(size_t)T_STEPS * (64 * HD) + ci] = h_new;             // hx
        out[(size_t)T_STEPS * (64 * HD) + 64 * HD + ci] = c_new;   // cx
      }
      __syncthreads();
      if (tid == 0) release_flag(&aC[nb], t + 1);
    }
  }
}

// ---- prep kernels ----------------------------------------------------------
__global__ void xconv_kernel(const float* __restrict__ x,
                             unsigned short* __restrict__ xbf, int n4) {
  int idx = blockIdx.x * blockDim.x + threadIdx.x;
  int stride = gridDim.x * blockDim.x;
  for (int i = idx; i < n4; i += stride) {
    float4 v = ((const float4*)x)[i];
    ushort4 o;
    o.x = f2bf(v.x); o.y = f2bf(v.y); o.z = f2bf(v.z); o.w = f2bf(v.w);
    ((ushort4*)xbf)[i] = o;
  }
}

__global__ void wconv_kernel(const float* __restrict__ Wf, const float* __restrict__ Wi,
                             const float* __restrict__ Wu, const float* __restrict__ Wo,
                             const float* __restrict__ bfv, const float* __restrict__ biv,
                             const float* __restrict__ buv, const float* __restrict__ bov,
                             unsigned short* __restrict__ Wbf, float* __restrict__ bias_cat) {
  const int n = blockIdx.x;                 // 0..4095
  const int gate = n >> 10, r = n & 1023;
  const float* W = gate == 0 ? Wf : gate == 1 ? Wi : gate == 2 ? Wu : Wo;
  const float* src = W + (size_t)r * DHK;
  unsigned short* dst = Wbf + (size_t)n * DHK;
  for (int k = threadIdx.x; k < DHK; k += 256) dst[k] = f2bf(src[k]);
  if (threadIdx.x == 0) {
    const float* bsrc = gate == 0 ? bfv : gate == 1 ? biv : gate == 2 ? buv : bov;
    bias_cat[n] = bsrc[r];
  }
}

__global__ void qcw_kernel(const float* __restrict__ qcv, const float* __restrict__ qcg,
                           unsigned short* __restrict__ qcw) {
  const int row = blockIdx.x * 4 + (threadIdx.x >> 6);  // 0..2047 (= d*1024+o)
  const int lane = threadIdx.x & 63;
  const float* v = qcv + (size_t)row * HD;
  float ss = 0.0f;
#pragma unroll
  for (int j = 0; j < 16; ++j) { float a = v[j * 64 + lane]; ss += a * a; }
#pragma unroll
  for (int off = 32; off > 0; off >>= 1) ss += __shfl_xor(ss, off);
  const float scale = qcg[row] / sqrtf(ss);
#pragma unroll
  for (int j = 0; j < 16; ++j)
    qcw[(size_t)row * HD + j * 64 + lane] = f2bf(v[j * 64 + lane] * scale);
}

__global__ void init_state_kernel(unsigned short* __restrict__ hbf,
                                  float* __restrict__ c_state,
                                  int* __restrict__ flags) {
  int i = blockIdx.x * blockDim.x + threadIdx.x;  // 65536 launched
  hbf[i] = 0;
  c_state[i] = 0.0f;
  if (i < 768) flags[i] = 0;
}

// ---- launcher --------------------------------------------------------------
extern "C" void kernel_launch(void* const* d_in, const int* in_sizes, int n_in,
                              void* d_out, int out_size, void* d_ws, size_t ws_size,
                              hipStream_t stream) {
  const float* x   = (const float*)d_in[0];
  const float* Wf  = (const float*)d_in[1];
  const float* bfv = (const float*)d_in[2];
  const float* Wi  = (const float*)d_in[3];
  const float* biv = (const float*)d_in[4];
  const float* Wu  = (const float*)d_in[5];
  const float* buv = (const float*)d_in[6];
  const float* Wo  = (const float*)d_in[7];
  const float* bov = (const float*)d_in[8];
  const float* qcv = (const float*)d_in[9];
  const float* qcg = (const float*)d_in[10];
  const float* qcb = (const float*)d_in[11];
  float* out = (float*)d_out;

  char* p = (char*)d_ws;
  auto alloc = [&](size_t bytes) {
    char* r = p; p += (bytes + 255) & ~(size_t)255; return r;
  };
  unsigned short* Xbf  = (unsigned short*)alloc((size_t)T_STEPS * 64 * HD * 2);
  unsigned short* Wbf  = (unsigned short*)alloc((size_t)4096 * DHK * 2);
  unsigned short* qcw  = (unsigned short*)alloc((size_t)2 * HD * HD * 2);
  float* bias_cat      = (float*)alloc((size_t)4096 * 4);
  unsigned short* Gbf  = (unsigned short*)alloc((size_t)256 * HD * 2);
  unsigned short* G2bf = (unsigned short*)alloc((size_t)256 * HD * 2);
  unsigned short* hbf  = (unsigned short*)alloc((size_t)64 * HD * 2);
  float* c_state       = (float*)alloc((size_t)64 * HD * 4);
  int* flags           = (int*)alloc(768 * 4);

  init_state_kernel<<<256, 256, 0, stream>>>(hbf, c_state, flags);
  xconv_kernel<<<2048, 256, 0, stream>>>(x, Xbf, T_STEPS * 64 * HD / 4);
  wconv_kernel<<<4096, 256, 0, stream>>>(Wf, Wi, Wu, Wo, bfv, biv, buv, bov,
                                         Wbf, bias_cat);
  qcw_kernel<<<512, 256, 0, stream>>>(qcv, qcg, qcw);

  qlstm_persist<<<256, 256, 0, stream>>>(
      Xbf, Wbf, qcw, bias_cat, qcb, Gbf, G2bf, hbf, c_state, out,
      flags, flags + 256, flags + 512);
}

// Round 3
// 6415.490 us; speedup vs baseline: 3.2725x; 3.2725x over previous
//
#include <hip/hip_runtime.h>
#include <cstdint>
#include <cstddef>

typedef float f32x4 __attribute__((ext_vector_type(4)));
typedef __bf16 bf16x8 __attribute__((ext_vector_type(8)));

#define T_STEPS 256
#define HD      1024
#define DHK     2048

__device__ __forceinline__ unsigned short f2bf(float f) {
  union { float f; unsigned u; } v; v.f = f;
  unsigned r = v.u + 0x7fffu + ((v.u >> 16) & 1u);  // RNE, inputs finite
  return (unsigned short)(r >> 16);
}

__device__ __forceinline__ float fast_sigmoid(float x) {
  return 1.0f / (1.0f + __expf(-x));
}
__device__ __forceinline__ float fast_tanh(float x) {
  float e = __expf(2.0f * x);
  return (e - 1.0f) / (e + 1.0f);
}

__device__ __forceinline__ f32x4 mfma16(bf16x8 a, bf16x8 b, f32x4 c) {
  return __builtin_amdgcn_mfma_f32_16x16x32_bf16(a, b, c, 0, 0, 0);
}

// ---- fine-grained coherent data path (bypass L1/L2, hit MALL) --------------
// Loads/stores tagged sc0 sc1 go to the device coherence point; no cache-wide
// fences (buffer_inv / buffer_wbl2) are needed anywhere.
#define LOADC(dst, vofs, base, IMM)                                            \
  asm volatile("global_load_dwordx4 %0, %1, %2 offset:" IMM " sc0 sc1"         \
               : "=v"(dst) : "v"(vofs), "s"(base) : "memory")

#define L8(st, vofs, base)                                                     \
  LOADC(st[0], vofs, base, "0");   LOADC(st[1], vofs, base, "64");             \
  LOADC(st[2], vofs, base, "128"); LOADC(st[3], vofs, base, "192");            \
  LOADC(st[4], vofs, base, "256"); LOADC(st[5], vofs, base, "320");            \
  LOADC(st[6], vofs, base, "384"); LOADC(st[7], vofs, base, "448")

#define WAITV0()                                                               \
  do { asm volatile("s_waitcnt vmcnt(0)" ::: "memory");                        \
       __builtin_amdgcn_sched_barrier(0); } while (0)

#define MF8(st, w, accv)                                                       \
  accv = mfma16(st[0], (w)[0], accv); accv = mfma16(st[1], (w)[1], accv);      \
  accv = mfma16(st[2], (w)[2], accv); accv = mfma16(st[3], (w)[3], accv);      \
  accv = mfma16(st[4], (w)[4], accv); accv = mfma16(st[5], (w)[5], accv);      \
  accv = mfma16(st[6], (w)[6], accv); accv = mfma16(st[7], (w)[7], accv)

__device__ __forceinline__ void storec8(void* p, ushort4 v) {
  asm volatile("global_store_dwordx2 %0, %1, off sc0 sc1"
               :: "v"(p), "v"(v) : "memory");
}
__device__ __forceinline__ void storec2(void* p, unsigned short v) {
  unsigned vv = v;
  asm volatile("global_store_short %0, %1, off sc0 sc1"
               :: "v"(p), "v"(vv) : "memory");
}

// Producer: caller did __syncthreads() (drains all waves' vmcnt; sc0sc1 data
// stores are acked at the coherence point). Just publish the flag.
__device__ __forceinline__ void release_flag(int* f, int v) {
  asm volatile("s_waitcnt vmcnt(0)" ::: "memory");
  __hip_atomic_store(f, v, __ATOMIC_RELAXED, __HIP_MEMORY_SCOPE_AGENT);
}
// Consumer poll: relaxed agent loads bypass the (non-coherent) local L2.
__device__ __forceinline__ void wait_ge(const int* f, int v) {
  while (__hip_atomic_load(f, __ATOMIC_RELAXED, __HIP_MEMORY_SCOPE_AGENT) < v)
    __builtin_amdgcn_s_sleep(2);
  asm volatile("" ::: "memory");
}

// ---- persistent kernel: all 256 timesteps, 256 blocks (1/CU), 4 waves -----
//   A: G[gate*64+b][h]   = act(comb @ W[n0..n0+16]^T + bias)   K=2048
//   B: G2[gate*64+b][h]  = tanh(G @ qcw0[n0..]^T + qcb0)       K=1024
//   C: rows (gate,16-batch) -> f/i/g/o in one thread -> cell update, K=1024
__global__ __launch_bounds__(256, 1) void qlstm_persist(
    const unsigned short* __restrict__ Xbf,
    const unsigned short* __restrict__ Wbf,      // [4096][2048]
    const unsigned short* __restrict__ qcw,      // [2][1024][1024]
    const float* __restrict__ bias_cat,          // [4096]
    const float* __restrict__ qcb,               // [2][1024]
    unsigned short* __restrict__ Gbf,            // [256][1024]
    unsigned short* __restrict__ G2bf,           // [256][1024]
    unsigned short* __restrict__ hbf,            // [64][1024]
    float* __restrict__ c_state,                 // [64][1024]
    float* __restrict__ out,
    int* __restrict__ aA, int* __restrict__ aB, int* __restrict__ aC) {
  const int nb = blockIdx.x, tid = threadIdx.x;
  const int wv = tid >> 6, lane = tid & 63;
  const int l15 = lane & 15, l16 = lane >> 4;
  const int q = nb >> 6;            // A: gate | B: row-gate | C: batch-tile
  const int n0 = (nb & 63) * 16;    // col offset within 1024
  const int kb = wv * 256;          // wave K-slice base

  __shared__ __align__(16) float red[4][16][68];  // [wave][col][row(padded)]

  // ---- weight/bias preload into registers (held across all 256 steps) ----
  bf16x8 wA[16], wB[8], wC[8];
  {
    const unsigned short* wrow = Wbf + (size_t)(nb * 16 + l15) * DHK;
#pragma unroll
    for (int s = 0; s < 8; ++s)
      wA[s] = *(const bf16x8*)&wrow[kb + s * 32 + l16 * 8];
#pragma unroll
    for (int s = 0; s < 8; ++s)
      wA[8 + s] = *(const bf16x8*)&wrow[1024 + kb + s * 32 + l16 * 8];
    const unsigned short* qrow0 = qcw + (size_t)(n0 + l15) * HD;
    const unsigned short* qrow1 = qrow0 + (size_t)HD * HD;
#pragma unroll
    for (int s = 0; s < 8; ++s) {
      wB[s] = *(const bf16x8*)&qrow0[kb + s * 32 + l16 * 8];
      wC[s] = *(const bf16x8*)&qrow1[kb + s * 32 + l16 * 8];
    }
  }
  const f32x4 biasA = *(const f32x4*)&bias_cat[nb * 16 + (tid & 3) * 4];
  const f32x4 biasB = *(const f32x4*)&qcb[n0 + (tid & 3) * 4];
  const float biasC = qcb[HD + n0 + (tid & 15)];

  const int erow = tid >> 2, ecb = (tid & 3) * 4;  // A/B epilogue coords
  const int bl = tid >> 4, cc = tid & 15;          // C epilogue coords

  // byte voffsets for coherent A-operand loads (constant across steps)
  int vofsAB[4], vofsC[4];
#pragma unroll
  for (int mt = 0; mt < 4; ++mt) {
    vofsAB[mt] = (((mt * 16 + l15) * HD) + kb + l16 * 8) * 2;
    vofsC[mt]  = (((mt * 64 + q * 16 + l15) * HD) + kb + l16 * 8) * 2;
  }
  const unsigned short* hB  = hbf;
  const unsigned short* gB  = Gbf + (size_t)(q * 64) * HD;
  const unsigned short* g2B = G2bf;

  for (int t = 0; t < T_STEPS; ++t) {
    // ================= phase A: gates =================
    {
      f32x4 acc[4] = {};
      // x-half first: independent of the recurrence -> overlaps handoff wait
      const unsigned short* xb = Xbf + (size_t)t * (64 * HD);
#pragma unroll
      for (int s = 0; s < 8; ++s) {
        const int k = kb + s * 32 + l16 * 8;
#pragma unroll
        for (int mt = 0; mt < 4; ++mt) {
          bf16x8 a = *(const bf16x8*)&xb[(size_t)(mt * 16 + l15) * HD + k];
          acc[mt] = mfma16(a, wA[s], acc[mt]);
        }
      }
      wait_ge(&aC[tid], t);                       // h(t-1) ready (all C blocks)
      __syncthreads();
      {
        bf16x8 s0[8], s1[8], s2[8], s3[8];
        L8(s0, vofsAB[0], hB); L8(s1, vofsAB[1], hB);
        L8(s2, vofsAB[2], hB); L8(s3, vofsAB[3], hB);
        WAITV0();
        MF8(s0, wA + 8, acc[0]); MF8(s1, wA + 8, acc[1]);
        MF8(s2, wA + 8, acc[2]); MF8(s3, wA + 8, acc[3]);
      }
#pragma unroll
      for (int mt = 0; mt < 4; ++mt)
        *(f32x4*)&red[wv][l15][mt * 16 + l16 * 4] = acc[mt];
      __syncthreads();
      ushort4 pk;
#pragma unroll
      for (int i = 0; i < 4; ++i) {
        float v = red[0][ecb + i][erow] + red[1][ecb + i][erow] +
                  red[2][ecb + i][erow] + red[3][ecb + i][erow] + biasA[i];
        v = (q == 2) ? fast_tanh(v) : fast_sigmoid(v);
        ((unsigned short*)&pk)[i] = f2bf(v);
      }
      storec8(&Gbf[(size_t)(q * 64 + erow) * HD + n0 + ecb], pk);
      __syncthreads();
      if (tid == 0) release_flag(&aA[nb], t + 1);
    }
    // ================= phase B: qc depth 0 =================
    {
      if (tid < 64) wait_ge(&aA[q * 64 + tid], t + 1);  // our gate's producers
      __syncthreads();
      f32x4 acc[4] = {};
      {
        bf16x8 s0[8], s1[8], s2[8], s3[8];
        L8(s0, vofsAB[0], gB); L8(s1, vofsAB[1], gB);
        L8(s2, vofsAB[2], gB); L8(s3, vofsAB[3], gB);
        WAITV0();
        MF8(s0, wB, acc[0]); MF8(s1, wB, acc[1]);
        MF8(s2, wB, acc[2]); MF8(s3, wB, acc[3]);
      }
#pragma unroll
      for (int mt = 0; mt < 4; ++mt)
        *(f32x4*)&red[wv][l15][mt * 16 + l16 * 4] = acc[mt];
      __syncthreads();
      ushort4 pk;
#pragma unroll
      for (int i = 0; i < 4; ++i) {
        float v = red[0][ecb + i][erow] + red[1][ecb + i][erow] +
                  red[2][ecb + i][erow] + red[3][ecb + i][erow] + biasB[i];
        ((unsigned short*)&pk)[i] = f2bf(fast_tanh(v));
      }
      storec8(&G2bf[(size_t)(q * 64 + erow) * HD + n0 + ecb], pk);
      __syncthreads();
      if (tid == 0) release_flag(&aB[nb], t + 1);
    }
    // ================= phase C: qc depth 1 + cell update =================
    {
      wait_ge(&aB[tid], t + 1);                   // needs all of G2's K
      __syncthreads();
      f32x4 acc[4] = {};
      {
        bf16x8 s0[8], s1[8], s2[8], s3[8];
        L8(s0, vofsC[0], g2B); L8(s1, vofsC[1], g2B);
        L8(s2, vofsC[2], g2B); L8(s3, vofsC[3], g2B);
        WAITV0();
        MF8(s0, wC, acc[0]); MF8(s1, wC, acc[1]);
        MF8(s2, wC, acc[2]); MF8(s3, wC, acc[3]);
      }
#pragma unroll
      for (int mt = 0; mt < 4; ++mt)
        *(f32x4*)&red[wv][l15][mt * 16 + l16 * 4] = acc[mt];
      __syncthreads();
      float gv[4];
#pragma unroll
      for (int g = 0; g < 4; ++g) {
        float v = red[0][cc][g * 16 + bl] + red[1][cc][g * 16 + bl] +
                  red[2][cc][g * 16 + bl] + red[3][cc][g * 16 + bl] + biasC;
        gv[g] = fast_tanh(v);
      }
      const int ci = (q * 16 + bl) * HD + n0 + cc;
      const float c_new = gv[0] * c_state[ci] + gv[1] * gv[2];
      const float h_new = gv[3] * fast_tanh(c_new);
      c_state[ci] = c_new;
      out[(size_t)t * (64 * HD) + ci] = h_new;
      storec2(&hbf[ci], f2bf(h_new));
      if (t == T_STEPS - 1) {
        out[(size_t)T_STEPS * (64 * HD) + ci] = h_new;             // hx
        out[(size_t)T_STEPS * (64 * HD) + 64 * HD + ci] = c_new;   // cx
      }
      __syncthreads();
      if (tid == 0) release_flag(&aC[nb], t + 1);
    }
  }
}

// ---- prep kernels ----------------------------------------------------------
__global__ void xconv_kernel(const float* __restrict__ x,
                             unsigned short* __restrict__ xbf, int n4) {
  int idx = blockIdx.x * blockDim.x + threadIdx.x;
  int stride = gridDim.x * blockDim.x;
  for (int i = idx; i < n4; i += stride) {
    float4 v = ((const float4*)x)[i];
    ushort4 o;
    o.x = f2bf(v.x); o.y = f2bf(v.y); o.z = f2bf(v.z); o.w = f2bf(v.w);
    ((ushort4*)xbf)[i] = o;
  }
}

__global__ void wconv_kernel(const float* __restrict__ Wf, const float* __restrict__ Wi,
                             const float* __restrict__ Wu, const float* __restrict__ Wo,
                             const float* __restrict__ bfv, const float* __restrict__ biv,
                             const float* __restrict__ buv, const float* __restrict__ bov,
                             unsigned short* __restrict__ Wbf, float* __restrict__ bias_cat) {
  const int n = blockIdx.x;                 // 0..4095
  const int gate = n >> 10, r = n & 1023;
  const float* W = gate == 0 ? Wf : gate == 1 ? Wi : gate == 2 ? Wu : Wo;
  const float* src = W + (size_t)r * DHK;
  unsigned short* dst = Wbf + (size_t)n * DHK;
  for (int k = threadIdx.x; k < DHK; k += 256) dst[k] = f2bf(src[k]);
  if (threadIdx.x == 0) {
    const float* bsrc = gate == 0 ? bfv : gate == 1 ? biv : gate == 2 ? buv : bov;
    bias_cat[n] = bsrc[r];
  }
}

__global__ void qcw_kernel(const float* __restrict__ qcv, const float* __restrict__ qcg,
                           unsigned short* __restrict__ qcw) {
  const int row = blockIdx.x * 4 + (threadIdx.x >> 6);  // 0..2047 (= d*1024+o)
  const int lane = threadIdx.x & 63;
  const float* v = qcv + (size_t)row * HD;
  float ss = 0.0f;
#pragma unroll
  for (int j = 0; j < 16; ++j) { float a = v[j * 64 + lane]; ss += a * a; }
#pragma unroll
  for (int off = 32; off > 0; off >>= 1) ss += __shfl_xor(ss, off);
  const float scale = qcg[row] / sqrtf(ss);
#pragma unroll
  for (int j = 0; j < 16; ++j)
    qcw[(size_t)row * HD + j * 64 + lane] = f2bf(v[j * 64 + lane] * scale);
}

__global__ void init_state_kernel(unsigned short* __restrict__ hbf,
                                  float* __restrict__ c_state,
                                  int* __restrict__ flags) {
  int i = blockIdx.x * blockDim.x + threadIdx.x;  // 65536 launched
  hbf[i] = 0;
  c_state[i] = 0.0f;
  if (i < 768) flags[i] = 0;
}

// ---- launcher --------------------------------------------------------------
extern "C" void kernel_launch(void* const* d_in, const int* in_sizes, int n_in,
                              void* d_out, int out_size, void* d_ws, size_t ws_size,
                              hipStream_t stream) {
  const float* x   = (const float*)d_in[0];
  const float* Wf  = (const float*)d_in[1];
  const float* bfv = (const float*)d_in[2];
  const float* Wi  = (const float*)d_in[3];
  const float* biv = (const float*)d_in[4];
  const float* Wu  = (const float*)d_in[5];
  const float* buv = (const float*)d_in[6];
  const float* Wo  = (const float*)d_in[7];
  const float* bov = (const float*)d_in[8];
  const float* qcv = (const float*)d_in[9];
  const float* qcg = (const float*)d_in[10];
  const float* qcb = (const float*)d_in[11];
  float* out = (float*)d_out;

  char* p = (char*)d_ws;
  auto alloc = [&](size_t bytes) {
    char* r = p; p += (bytes + 255) & ~(size_t)255; return r;
  };
  unsigned short* Xbf  = (unsigned short*)alloc((size_t)T_STEPS * 64 * HD * 2);
  unsigned short* Wbf  = (unsigned short*)alloc((size_t)4096 * DHK * 2);
  unsigned short* qcw  = (unsigned short*)alloc((size_t)2 * HD * HD * 2);
  float* bias_cat      = (float*)alloc((size_t)4096 * 4);
  unsigned short* Gbf  = (unsigned short*)alloc((size_t)256 * HD * 2);
  unsigned short* G2bf = (unsigned short*)alloc((size_t)256 * HD * 2);
  unsigned short* hbf  = (unsigned short*)alloc((size_t)64 * HD * 2);
  float* c_state       = (float*)alloc((size_t)64 * HD * 4);
  int* flags           = (int*)alloc(768 * 4);

  init_state_kernel<<<256, 256, 0, stream>>>(hbf, c_state, flags);
  xconv_kernel<<<2048, 256, 0, stream>>>(x, Xbf, T_STEPS * 64 * HD / 4);
  wconv_kernel<<<4096, 256, 0, stream>>>(Wf, Wi, Wu, Wo, bfv, biv, buv, bov,
                                         Wbf, bias_cat);
  qcw_kernel<<<512, 256, 0, stream>>>(qcv, qcg, qcw);

  qlstm_persist<<<256, 256, 0, stream>>>(
      Xbf, Wbf, qcw, bias_cat, qcb, Gbf, G2bf, hbf, c_state, out,
      flags, flags + 256, flags + 512);
}